// Round 3
// baseline (62.232 us; speedup 1.0000x reference)
//
#include <hip/hip_runtime.h>

// x[64][16][8192] f32, J=4, LEVELS=13, eps 1e-5.
// masked_targets[j] = blockmean with block 2^(13-j)   (j=0..3 -> 8192,4096,2048,1024)
// masked_inputs[j]  = j==0 ? blockmean(8192) : blockmean(2^(13-j)) - blockmean(2^(14-j)), then BN
// Output [2][4][64][16][8192] f32.

#define NROWS 1024          // 64*16
#define ROWLEN 8192
#define STATS_STRIDE 16     // 15 floats padded to 16
// stats layout per row: [0]=m0, [1..2]=m1, [3..6]=m2, [7..14]=m3  (base (1<<j)-1, count 1<<j)

typedef float f32x4 __attribute__((ext_vector_type(4)));

__global__ __launch_bounds__(256) void row_stats_kernel(const float* __restrict__ x,
                                                        float* __restrict__ stats) {
    int row = blockIdx.x;                 // 0..1023
    const f32x4* xr = reinterpret_cast<const f32x4*>(x) + (size_t)row * (ROWLEN / 4);
    int t = threadIdx.x;                  // 0..255
    float s[8];
#pragma unroll
    for (int k = 0; k < 8; ++k) {
        f32x4 v = __builtin_nontemporal_load(&xr[t + 256 * k]);  // iter k = 1024-block k
        s[k] = (v.x + v.y) + (v.z + v.w);
    }
    __shared__ float red[8][4];
    __shared__ float m3s[8];
    int lane = t & 63, wave = t >> 6;
#pragma unroll
    for (int k = 0; k < 8; ++k) {
        float v = s[k];
#pragma unroll
        for (int off = 32; off; off >>= 1) v += __shfl_down(v, off, 64);
        if (lane == 0) red[k][wave] = v;
    }
    __syncthreads();
    if (t < 8) m3s[t] = (red[t][0] + red[t][1] + red[t][2] + red[t][3]) * (1.0f / 1024.0f);
    __syncthreads();
    if (t == 0) {
        float* o = stats + (size_t)row * STATS_STRIDE;
        float m2[4], m1[2];
#pragma unroll
        for (int k = 0; k < 4; ++k) m2[k] = 0.5f * (m3s[2 * k] + m3s[2 * k + 1]);
        m1[0] = 0.5f * (m2[0] + m2[1]);
        m1[1] = 0.5f * (m2[2] + m2[3]);
        float m0 = 0.5f * (m1[0] + m1[1]);
        o[0] = m0;
        o[1] = m1[0]; o[2] = m1[1];
        o[3] = m2[0]; o[4] = m2[1]; o[5] = m2[2]; o[6] = m2[3];
#pragma unroll
        for (int k = 0; k < 8; ++k) o[7 + k] = m3s[k];
    }
}

// One block per (j,c); 64 threads = one wave, thread b handles batch b.
__global__ __launch_bounds__(64) void bn_stats_kernel(const float* __restrict__ stats,
                                                      const float* __restrict__ gamma,
                                                      const float* __restrict__ beta,
                                                      float* __restrict__ bn /*[4][16][2]*/) {
    int j = blockIdx.x >> 4;
    int c = blockIdx.x & 15;
    int b = threadIdx.x;                  // 0..63
    const float* s = stats + (size_t)((b << 4) + c) * STATS_STRIDE;
    float sum = 0.f, sum2 = 0.f;
    float B = (float)(ROWLEN >> j);       // samples per block at level j
    if (j == 0) {
        float d = s[0];
        sum = d; sum2 = d * d;
    } else {
        int base = (1 << j) - 1;
        int pbase = (1 << (j - 1)) - 1;
        int nb = 1 << j;
        for (int k = 0; k < nb; ++k) {
            float d = s[base + k] - s[pbase + (k >> 1)];
            sum += d; sum2 += d * d;
        }
    }
    sum *= B; sum2 *= B;
#pragma unroll
    for (int off = 32; off; off >>= 1) {
        sum  += __shfl_down(sum, off, 64);
        sum2 += __shfl_down(sum2, off, 64);
    }
    if (b == 0) {
        const float N = 64.0f * 8192.0f;
        float mean = sum / N;
        float var = sum2 / N - mean * mean;
        float inv = rsqrtf(var + 1e-5f);
        float scale = gamma[(j << 4) + c] * inv;
        float shift = beta[(j << 4) + c] - mean * scale;
        bn[((j << 4) + c) * 2 + 0] = scale;
        bn[((j << 4) + c) * 2 + 1] = shift;
    }
}

// One block per output row (part,j,b,c): 8192 floats = 2048 float4.
// Run-values (<=8 piecewise-constant values per row) computed once into LDS,
// then a pure streaming nontemporal-store loop (8 x 16B per thread).
__global__ __launch_bounds__(256) void write_out_kernel(const float* __restrict__ stats,
                                                        const float* __restrict__ bn,
                                                        f32x4* __restrict__ out) {
    unsigned blk = blockIdx.x;            // [part][j][b][c]
    unsigned c = blk & 15u;
    unsigned b = (blk >> 4) & 63u;
    unsigned j = (blk >> 10) & 3u;
    unsigned part = blk >> 12;
    unsigned nb = 1u << j;                // runs per row
    unsigned t = threadIdx.x;
    __shared__ float sv[8];
    if (t < nb) {
        const float* s = stats + (size_t)((b << 4) + c) * STATS_STRIDE;
        float mj = s[nb - 1u + t];
        float v;
        if (part) {
            v = mj;                       // target: block mean
        } else {
            float d = mj;
            if (j > 0) d -= s[(nb >> 1) - 1u + (t >> 1)];
            unsigned jc = (j << 4) + c;
            v = d * bn[jc * 2] + bn[jc * 2 + 1];
        }
        sv[t] = v;
    }
    __syncthreads();
    f32x4* orow = out + (size_t)blk * 2048;
    unsigned sh = 3u - j;                 // run length in float4 = 2048>>j = 256<<sh
#pragma unroll
    for (unsigned i = 0; i < 8; ++i) {
        // pos = t + 256*i; run index = pos >> (11-j) = i >> (3-j)  (uniform, broadcast LDS read)
        float v = sv[i >> sh];
        f32x4 q = {v, v, v, v};
        __builtin_nontemporal_store(q, &orow[t + (i << 8)]);
    }
}

extern "C" void kernel_launch(void* const* d_in, const int* in_sizes, int n_in,
                              void* d_out, int out_size, void* d_ws, size_t ws_size,
                              hipStream_t stream) {
    const float* x     = (const float*)d_in[0];
    const float* gamma = (const float*)d_in[1];
    const float* beta  = (const float*)d_in[2];
    float* out = (float*)d_out;

    float* stats = (float*)d_ws;                           // 1024*16 floats = 64 KiB
    float* bn    = stats + (size_t)NROWS * STATS_STRIDE;   // 128 floats

    row_stats_kernel<<<NROWS, 256, 0, stream>>>(x, stats);
    bn_stats_kernel<<<64, 64, 0, stream>>>(stats, gamma, beta, bn);
    write_out_kernel<<<8192, 256, 0, stream>>>(stats, bn, (f32x4*)out);
}

// Round 4
// 58.049 us; speedup vs baseline: 1.0721x; 1.0721x over previous
//
#include <hip/hip_runtime.h>

// x[64][16][8192] f32, J=4, LEVELS=13, eps 1e-5.
// targets[j] = blockmean(2^(13-j)); inputs[j] = BN(blockmean(2^(13-j)) - blockmean(2^(14-j))), input[0]=BN(m0)
// Output [2][4][64][16][8192] f32.
// Kernel A: per row: read x-row, stats -> global, write 4 target rows (part=1).
// Kernel B: per block: inline bn reduce for (j,c), write 4 input rows (part=0).

#define STATS_STRIDE 16
// stats layout per row: [0]=m0, [1..2]=m1, [3..6]=m2, [7..14]=m3  (base (1<<j)-1, count 1<<j)

typedef float f32x4 __attribute__((ext_vector_type(4)));

__global__ __launch_bounds__(256) void stats_targets_kernel(const float* __restrict__ x,
                                                            float* __restrict__ stats,
                                                            f32x4* __restrict__ out) {
    int row = blockIdx.x;                 // 0..1023  (b=row>>4, c=row&15)
    int t = threadIdx.x;                  // 0..255
    const f32x4* xr = reinterpret_cast<const f32x4*>(x) + (size_t)row * 2048;
    float s[8];
#pragma unroll
    for (int k = 0; k < 8; ++k) {
        f32x4 v = __builtin_nontemporal_load(&xr[t + 256 * k]);  // iter k = 1024-block k
        s[k] = (v.x + v.y) + (v.z + v.w);
    }
    __shared__ float red[8][4];
    __shared__ float sb[16];              // pywt-ish stat row
    int lane = t & 63, wave = t >> 6;
#pragma unroll
    for (int k = 0; k < 8; ++k) {
        float v = s[k];
#pragma unroll
        for (int off = 32; off; off >>= 1) v += __shfl_down(v, off, 64);
        if (lane == 0) red[k][wave] = v;
    }
    __syncthreads();
    if (t < 8) sb[7 + t] = (red[t][0] + red[t][1] + red[t][2] + red[t][3]) * (1.0f / 1024.0f);
    __syncthreads();
    if (t == 0) {
        float m2[4], m1[2];
#pragma unroll
        for (int k = 0; k < 4; ++k) m2[k] = 0.5f * (sb[7 + 2 * k] + sb[7 + 2 * k + 1]);
        m1[0] = 0.5f * (m2[0] + m2[1]);
        m1[1] = 0.5f * (m2[2] + m2[3]);
        sb[0] = 0.5f * (m1[0] + m1[1]);
        sb[1] = m1[0]; sb[2] = m1[1];
        sb[3] = m2[0]; sb[4] = m2[1]; sb[5] = m2[2]; sb[6] = m2[3];
    }
    __syncthreads();
    if (t < 15) stats[(size_t)row * STATS_STRIDE + t] = sb[t];
    // write part=1 target rows for this (b,c), j=0..3
#pragma unroll
    for (int j = 0; j < 4; ++j) {
        f32x4* orow = out + ((size_t)(4 + j) * 1024 + row) * 2048;
        int sh = 3 - j;
#pragma unroll
        for (int i = 0; i < 8; ++i) {
            float v = sb[(1 << j) - 1 + (i >> sh)];   // run index uniform per i
            f32x4 q = {v, v, v, v};
            __builtin_nontemporal_store(q, &orow[t + (i << 8)]);
        }
    }
}

// block k (0..1023): j = k>>8, c = (k>>4)&15, b in {4*(k&15) .. +3}
__global__ __launch_bounds__(256) void inputs_kernel(const float* __restrict__ stats,
                                                     const float* __restrict__ gamma,
                                                     const float* __restrict__ beta,
                                                     f32x4* __restrict__ out) {
    int blk = blockIdx.x;
    int j = blk >> 8;
    int c = (blk >> 4) & 15;
    int bg = blk & 15;
    int t = threadIdx.x;
    __shared__ float ss[2];               // scale, shift
    if (t < 64) {                         // wave 0: bn reduce over 64 batch rows
        const float* s = stats + (size_t)((t << 4) + c) * STATS_STRIDE;
        float sum = 0.f, sum2 = 0.f;
        float B = (float)(8192 >> j);
        if (j == 0) {
            float d = s[0];
            sum = d; sum2 = d * d;
        } else {
            int base = (1 << j) - 1, pb = (1 << (j - 1)) - 1;
            for (int k = 0; k < (1 << j); ++k) {
                float d = s[base + k] - s[pb + (k >> 1)];
                sum += d; sum2 += d * d;
            }
        }
        sum *= B; sum2 *= B;
#pragma unroll
        for (int off = 32; off; off >>= 1) {
            sum  += __shfl_down(sum, off, 64);
            sum2 += __shfl_down(sum2, off, 64);
        }
        if (t == 0) {
            const float N = 64.0f * 8192.0f;
            float mean = sum / N;
            float var = sum2 / N - mean * mean;
            float inv = rsqrtf(var + 1e-5f);
            float sc = gamma[(j << 4) + c] * inv;
            ss[0] = sc;
            ss[1] = beta[(j << 4) + c] - mean * sc;
        }
    }
    __syncthreads();
    float sc = ss[0], sh0 = ss[1];
    int shr = 3 - j;
#pragma unroll
    for (int bb = 0; bb < 4; ++bb) {
        int row = (((bg << 2) + bb) << 4) + c;
        const float* s = stats + (size_t)row * STATS_STRIDE;
        f32x4* orow = out + ((size_t)j * 1024 + row) * 2048;
#pragma unroll
        for (int i = 0; i < 8; ++i) {
            int run = i >> shr;           // uniform
            float mj = s[(1 << j) - 1 + run];
            float d = (j == 0) ? mj : mj - s[(1 << (j - 1)) - 1 + (run >> 1)];
            float v = d * sc + sh0;
            f32x4 q = {v, v, v, v};
            __builtin_nontemporal_store(q, &orow[t + (i << 8)]);
        }
    }
}

extern "C" void kernel_launch(void* const* d_in, const int* in_sizes, int n_in,
                              void* d_out, int out_size, void* d_ws, size_t ws_size,
                              hipStream_t stream) {
    const float* x     = (const float*)d_in[0];
    const float* gamma = (const float*)d_in[1];
    const float* beta  = (const float*)d_in[2];
    f32x4* out = (f32x4*)d_out;
    float* stats = (float*)d_ws;          // 1024*16 floats = 64 KiB

    stats_targets_kernel<<<1024, 256, 0, stream>>>(x, stats, out);
    inputs_kernel<<<1024, 256, 0, stream>>>(stats, gamma, beta, out);
}

// Round 5
// 53.099 us; speedup vs baseline: 1.1720x; 1.0932x over previous
//
#include <hip/hip_runtime.h>

// x[64][16][8192] f32, J=4, LEVELS=13, eps 1e-5.
// targets[j] = blockmean(2^(13-j)); inputs[j] = BN(blockmean(2^(13-j)) - blockmean(2^(14-j))), input[0]=BN(m0)
// Output [2][4][64][16][8192] f32.
// Kernel A: per row: read x-row (NT), stats -> global, write 4 target rows (plain stores).
// Kernel B: per block: bn reduce for (j,c), write 4 input rows (plain stores).

#define STATS_STRIDE 16
// stats layout per row: [0]=m0, [1..2]=m1, [3..6]=m2, [7..14]=m3  (base (1<<j)-1, count 1<<j)

typedef float f32x4 __attribute__((ext_vector_type(4)));

__global__ __launch_bounds__(256) void stats_targets_kernel(const float* __restrict__ x,
                                                            float* __restrict__ stats,
                                                            f32x4* __restrict__ out) {
    int row = blockIdx.x;                 // 0..1023  (b=row>>4, c=row&15)
    int t = threadIdx.x;                  // 0..255
    const f32x4* xr = reinterpret_cast<const f32x4*>(x) + (size_t)row * 2048;
    float s[8];
#pragma unroll
    for (int k = 0; k < 8; ++k) {
        f32x4 v = __builtin_nontemporal_load(&xr[t + 256 * k]);  // iter k = 1024-block k
        s[k] = (v.x + v.y) + (v.z + v.w);
    }
    __shared__ float red[8][4];
    __shared__ float sb[16];
    int lane = t & 63, wave = t >> 6;
#pragma unroll
    for (int k = 0; k < 8; ++k) {
        float v = s[k];
#pragma unroll
        for (int off = 32; off; off >>= 1) v += __shfl_down(v, off, 64);
        if (lane == 0) red[k][wave] = v;
    }
    __syncthreads();
    if (t < 8) sb[7 + t] = (red[t][0] + red[t][1] + red[t][2] + red[t][3]) * (1.0f / 1024.0f);
    __syncthreads();
    if (t == 0) {
        float m2[4], m1[2];
#pragma unroll
        for (int k = 0; k < 4; ++k) m2[k] = 0.5f * (sb[7 + 2 * k] + sb[7 + 2 * k + 1]);
        m1[0] = 0.5f * (m2[0] + m2[1]);
        m1[1] = 0.5f * (m2[2] + m2[3]);
        sb[0] = 0.5f * (m1[0] + m1[1]);
        sb[1] = m1[0]; sb[2] = m1[1];
        sb[3] = m2[0]; sb[4] = m2[1]; sb[5] = m2[2]; sb[6] = m2[3];
    }
    __syncthreads();
    if (t < 15) stats[(size_t)row * STATS_STRIDE + t] = sb[t];
    // hoist all 15 run values into registers, then store-only loops
    float rv[15];
#pragma unroll
    for (int k = 0; k < 15; ++k) rv[k] = sb[k];
#pragma unroll
    for (int j = 0; j < 4; ++j) {
        f32x4* orow = out + ((size_t)(4 + j) * 1024 + row) * 2048;
        int sh = 3 - j;
#pragma unroll
        for (int i = 0; i < 8; ++i) {
            float v = rv[(1 << j) - 1 + (i >> sh)];
            f32x4 q = {v, v, v, v};
            orow[t + (i << 8)] = q;
        }
    }
}

// block k (0..1023): j = k>>8, c = (k>>4)&15, b in {4*(k&15) .. +3}
__global__ __launch_bounds__(256) void inputs_kernel(const float* __restrict__ stats,
                                                     const float* __restrict__ gamma,
                                                     const float* __restrict__ beta,
                                                     f32x4* __restrict__ out) {
    int blk = blockIdx.x;
    int j = blk >> 8;
    int c = (blk >> 4) & 15;
    int bg = blk & 15;
    int t = threadIdx.x;
    __shared__ float ss[2];               // scale, shift
    if (t < 64) {                         // wave 0: bn reduce over 64 batch rows
        const float* s = stats + (size_t)((t << 4) + c) * STATS_STRIDE;
        float sum = 0.f, sum2 = 0.f;
        float B = (float)(8192 >> j);
        if (j == 0) {
            float d = s[0];
            sum = d; sum2 = d * d;
        } else {
            int base = (1 << j) - 1, pb = (1 << (j - 1)) - 1;
            for (int k = 0; k < (1 << j); ++k) {
                float d = s[base + k] - s[pb + (k >> 1)];
                sum += d; sum2 += d * d;
            }
        }
        sum *= B; sum2 *= B;
#pragma unroll
        for (int off = 32; off; off >>= 1) {
            sum  += __shfl_down(sum, off, 64);
            sum2 += __shfl_down(sum2, off, 64);
        }
        if (t == 0) {
            const float N = 64.0f * 8192.0f;
            float mean = sum / N;
            float var = sum2 / N - mean * mean;
            float inv = rsqrtf(var + 1e-5f);
            float sc = gamma[(j << 4) + c] * inv;
            ss[0] = sc;
            ss[1] = beta[(j << 4) + c] - mean * sc;
        }
    }
    __syncthreads();
    float sc = ss[0], sh0 = ss[1];
    int shr = 3 - j;
#pragma unroll
    for (int bb = 0; bb < 4; ++bb) {
        int row = (((bg << 2) + bb) << 4) + c;
        const float* s = stats + (size_t)row * STATS_STRIDE;
        // hoist the <=8 output values for this row into registers first
        float rv[8];
#pragma unroll
        for (int r = 0; r < 8; ++r) {
            int run = (r < (1 << j)) ? r : 0;
            float mj = s[(1 << j) - 1 + run];
            float d = (j == 0) ? mj : mj - s[(1 << (j - 1)) - 1 + (run >> 1)];
            rv[r] = d * sc + sh0;
        }
        f32x4* orow = out + ((size_t)j * 1024 + row) * 2048;
#pragma unroll
        for (int i = 0; i < 8; ++i) {
            float v = rv[i >> shr];
            f32x4 q = {v, v, v, v};
            orow[t + (i << 8)] = q;
        }
    }
}

extern "C" void kernel_launch(void* const* d_in, const int* in_sizes, int n_in,
                              void* d_out, int out_size, void* d_ws, size_t ws_size,
                              hipStream_t stream) {
    const float* x     = (const float*)d_in[0];
    const float* gamma = (const float*)d_in[1];
    const float* beta  = (const float*)d_in[2];
    f32x4* out = (f32x4*)d_out;
    float* stats = (float*)d_ws;          // 1024*16 floats = 64 KiB

    stats_targets_kernel<<<1024, 256, 0, stream>>>(x, stats, out);
    inputs_kernel<<<1024, 256, 0, stream>>>(stats, gamma, beta, out);
}